// Round 16
// baseline (173.878 us; speedup 1.0000x reference)
//
#include <hip/hip_runtime.h>

#define N_BONDS 50000
#define N_EDGES 600000

typedef float f4 __attribute__((ext_vector_type(4)));
typedef unsigned short u16x4 __attribute__((ext_vector_type(4)));

__device__ __forceinline__ float bcastf(float v, int l) {
    return __builtin_bit_cast(float, __builtin_amdgcn_readlane(__builtin_bit_cast(int, v), l));
}
__device__ __forceinline__ f4 f4zero() { return (f4){0.f, 0.f, 0.f, 0.f}; }
__device__ __forceinline__ void fma4(f4& a, float s, const f4& b) {
    a.x = fmaf(s, b.x, a.x); a.y = fmaf(s, b.y, a.y);
    a.z = fmaf(s, b.z, a.z); a.w = fmaf(s, b.w, a.w);
}
__device__ __forceinline__ float bf2f(unsigned short u) {
    return __builtin_bit_cast(float, ((unsigned)u) << 16);
}
__device__ __forceinline__ unsigned short f2bf(float f) {   // RNE
    unsigned u = __builtin_bit_cast(unsigned, f);
    return (unsigned short)((u + 0x7fffu + ((u >> 16) & 1u)) >> 16);
}
__device__ __forceinline__ f4 cvt4(u16x4 u) {
    return (f4){bf2f(u.x), bf2f(u.y), bf2f(u.z), bf2f(u.w)};
}

// ---- K1: bondKb = bf16(bond @ Ktop) (R13-proven premul) ----
__global__ __launch_bounds__(256, 4)
void premul_bond(const float* __restrict__ bond, const float* __restrict__ Kmat,
                 unsigned short* __restrict__ bondKb) {
    __shared__ float ldsK[64 * 64];   // 16 KB: Ktop
    const int tid = threadIdx.x, lane = tid & 63, wid = tid >> 6;
    {
        const f4* K4 = (const f4*)Kmat;            // Ktop = first 1024 f4
        f4* L4 = (f4*)ldsK;
        #pragma unroll
        for (int i = 0; i < 4; ++i) L4[tid + i * 256] = K4[tid + i * 256];
    }
    __syncthreads();
    const int row0 = blockIdx.x * 32 + wid * 8;
    if (row0 >= N_BONDS) return;

    float rowv[8], acc[8];
    #pragma unroll
    for (int r = 0; r < 8; ++r) {
        int ri = row0 + r; if (ri >= N_BONDS) ri = N_BONDS - 1;
        rowv[r] = bond[ri * 64 + lane];
        acc[r]  = 0.f;
    }
    #pragma unroll 4
    for (int d = 0; d < 64; ++d) {
        const float k = ldsK[d * 64 + lane];       // lane = output unit
        #pragma unroll
        for (int r = 0; r < 8; ++r)
            acc[r] = fmaf(bcastf(rowv[r], d), k, acc[r]);
    }
    #pragma unroll
    for (int r = 0; r < 8; ++r)
        if (row0 + r < N_BONDS)
            bondKb[(row0 + r) * 64 + lane] = f2bf(acc[r]);
}

// ---- K2: edge-parallel segsum; uniform 64 edges/wave; atomics merge runs ----
__global__ __launch_bounds__(256, 8)   // VGPR cap 64 -> high occupancy
void edge_segsum(const unsigned short* __restrict__ bondKb,  // [N_BONDS][64] bf16
                 const float* __restrict__ sph,              // [N_EDGES][64]
                 const int*   __restrict__ edges,            // [N_EDGES][2]
                 float* __restrict__ outG,                    // [N_BONDS][64] (zeroed)
                 float* __restrict__ Sbuf)                    // [N_BONDS][64] (zeroed)
{
    const int tid  = threadIdx.x;
    const int lane = tid & 63;
    const int wid  = tid >> 6;
    const int fl   = lane & 15;   // f4-column within row
    const int sg   = lane >> 4;   // edge-within-quad

    const int W  = blockIdx.x * 4 + wid;
    const int e0 = W * 64;
    if (e0 >= N_EDGES) return;

    const int2 p = ((const int2*)edges)[e0 + lane];   // 64-edge window, coalesced
    const u16x4* bk4 = (const u16x4*)bondKb;
    const f4*    s4  = (const f4*)sph;

    f4 aG = f4zero(), aS = f4zero();
    int cur = __builtin_amdgcn_readlane(p.x, 0);

    auto closeseg = [&](int s) {
        f4 g = aG, v = aS;
        g.x += __shfl_xor(g.x, 16); g.y += __shfl_xor(g.y, 16);
        g.z += __shfl_xor(g.z, 16); g.w += __shfl_xor(g.w, 16);
        g.x += __shfl_xor(g.x, 32); g.y += __shfl_xor(g.y, 32);
        g.z += __shfl_xor(g.z, 32); g.w += __shfl_xor(g.w, 32);
        v.x += __shfl_xor(v.x, 16); v.y += __shfl_xor(v.y, 16);
        v.z += __shfl_xor(v.z, 16); v.w += __shfl_xor(v.w, 16);
        v.x += __shfl_xor(v.x, 32); v.y += __shfl_xor(v.y, 32);
        v.z += __shfl_xor(v.z, 32); v.w += __shfl_xor(v.w, 32);
        if (sg == 0) {                                // 16 lanes cover the 64-col row
            float* og = &outG[s * 64 + fl * 4];
            unsafeAtomicAdd(og + 0, g.x); unsafeAtomicAdd(og + 1, g.y);
            unsafeAtomicAdd(og + 2, g.z); unsafeAtomicAdd(og + 3, g.w);
            float* os = &Sbuf[s * 64 + fl * 4];
            unsafeAtomicAdd(os + 0, v.x); unsafeAtomicAdd(os + 1, v.y);
            unsafeAtomicAdd(os + 2, v.z); unsafeAtomicAdd(os + 3, v.w);
        }
        aG = f4zero(); aS = f4zero();
    };

    auto accq = [&](int q, u16x4 uv, f4 sv) {
        const f4 gv = cvt4(uv);
        const int sA = __builtin_amdgcn_readlane(p.x, 4 * q);
        const int sD = __builtin_amdgcn_readlane(p.x, 4 * q + 3);
        if (sA == cur && sD == cur) {                 // whole quad in open run
            aG += gv; aS += sv;
        } else {
            #pragma unroll
            for (int j = 0; j < 4; ++j) {             // wave-uniform boundary path
                const int se = __builtin_amdgcn_readlane(p.x, 4 * q + j);
                if (se != cur) { closeseg(cur); cur = se; }
                const float m = (sg == j) ? 1.f : 0.f;
                fma4(aG, m, gv); fma4(aS, m, sv);
            }
        }
    };

    auto iss = [&](int q, u16x4& uv, f4& sv) {
        const int nbr = __shfl(p.y, 4 * q + sg);
        uv = bk4[nbr * 16 + fl];                      // 8B/lane gather (bf16 row)
        sv = s4[(e0 + 4 * q + sg) * 16 + fl];         // 16B/lane stream
    };

    u16x4 uA, uB; f4 vA, vB;
    iss(0, uA, vA); iss(1, uB, vB);
    #pragma unroll
    for (int q = 0; q < 16; q += 2) {                 // static: 16 quads/window
        if (q + 2 < 16) { accq(q, uA, vA); iss(q + 2, uA, vA); }
        else              accq(q, uA, vA);
        if (q + 3 < 16) { accq(q + 1, uB, vB); iss(q + 3, uB, vB); }
        else              accq(q + 1, uB, vB);
    }
    closeseg(cur);
}

// ---- K3: out = out + Sbuf @ Kbot + bias (R11-proven) ----
__global__ __launch_bounds__(256, 4)
void finish_mm(const float* __restrict__ Sbuf, const float* __restrict__ Kmat,
               const float* __restrict__ bias, float* __restrict__ out) {
    __shared__ float ldsK[64 * 64];   // 16 KB: Kbot
    const int tid = threadIdx.x, lane = tid & 63, wid = tid >> 6;
    {
        const f4* K4 = (const f4*)Kmat;            // Kbot = f4 index 1024..2047
        f4* L4 = (f4*)ldsK;
        #pragma unroll
        for (int i = 0; i < 4; ++i) L4[tid + i * 256] = K4[1024 + tid + i * 256];
    }
    __syncthreads();
    const int row0 = blockIdx.x * 32 + wid * 8;
    if (row0 >= N_BONDS) return;

    const float bl = bias[lane];
    float rowv[8], acc[8];
    #pragma unroll
    for (int r = 0; r < 8; ++r) {
        int ri = row0 + r; if (ri >= N_BONDS) ri = N_BONDS - 1;
        rowv[r] = Sbuf[ri * 64 + lane];
        acc[r]  = out[ri * 64 + lane] + bl;
    }
    #pragma unroll 4
    for (int d = 0; d < 64; ++d) {
        const float k = ldsK[d * 64 + lane];
        #pragma unroll
        for (int r = 0; r < 8; ++r)
            acc[r] = fmaf(bcastf(rowv[r], d), k, acc[r]);
    }
    #pragma unroll
    for (int r = 0; r < 8; ++r)
        if (row0 + r < N_BONDS)
            __builtin_nontemporal_store(acc[r], &out[(row0 + r) * 64 + lane]);
}

extern "C" void kernel_launch(void* const* d_in, const int* in_sizes, int n_in,
                              void* d_out, int out_size, void* d_ws, size_t ws_size,
                              hipStream_t stream) {
    const float* bond  = (const float*)d_in[0];
    const float* sph   = (const float*)d_in[1];
    const int*   edges = (const int*)d_in[2];
    const float* Kmat  = (const float*)d_in[3];
    const float* bias  = (const float*)d_in[4];
    float* out = (float*)d_out;

    const size_t rowBytes = (size_t)N_BONDS * 64 * sizeof(float);   // 12.8 MB
    float*          Sbuf   = (float*)d_ws;
    unsigned short* bondKb = (unsigned short*)((char*)d_ws + rowBytes);

    hipMemsetAsync(out,  0, rowBytes, stream);
    hipMemsetAsync(Sbuf, 0, rowBytes, stream);

    premul_bond<<<(N_BONDS + 31) / 32, 256, 0, stream>>>(bond, Kmat, bondKb);

    const int nwaves  = N_EDGES / 64;                       // 9375, uniform
    const int nblocks = (nwaves + 3) / 4;                   // 2344
    edge_segsum<<<nblocks, 256, 0, stream>>>(bondKb, sph, edges, out, Sbuf);

    finish_mm<<<(N_BONDS + 31) / 32, 256, 0, stream>>>(Sbuf, Kmat, bias, out);
}

// Round 17
// 88.930 us; speedup vs baseline: 1.9552x; 1.9552x over previous
//
#include <hip/hip_runtime.h>

#define N_BONDS 50000
#define N_EDGES 600000
#define R_BONDS 8
#define THREADS 256
#define BONDS_PER_BLOCK 32     // 4 waves * 8 bonds
#define STARTS_BLOCKS ((N_EDGES + 255) / 256)          // 2344
#define PREMUL_BLOCKS ((N_BONDS + 31) / 32)            // 1563
#define MAIN_BBLKS ((N_BONDS + BONDS_PER_BLOCK - 1) / BONDS_PER_BLOCK)  // 1563

typedef float f4 __attribute__((ext_vector_type(4)));
typedef unsigned short u16x4 __attribute__((ext_vector_type(4)));

__device__ __forceinline__ float bcastf(float v, int l) {
    return __builtin_bit_cast(float, __builtin_amdgcn_readlane(__builtin_bit_cast(int, v), l));
}
__device__ __forceinline__ f4 f4zero() { return (f4){0.f, 0.f, 0.f, 0.f}; }
__device__ __forceinline__ void fma4(f4& a, float s, const f4& b) {
    a.x = fmaf(s, b.x, a.x); a.y = fmaf(s, b.y, a.y);
    a.z = fmaf(s, b.z, a.z); a.w = fmaf(s, b.w, a.w);
}
__device__ __forceinline__ float bf2f(unsigned short u) {
    return __builtin_bit_cast(float, ((unsigned)u) << 16);
}
__device__ __forceinline__ unsigned short f2bf(float f) {   // RNE
    unsigned u = __builtin_bit_cast(unsigned, f);
    return (unsigned short)((u + 0x7fffu + ((u >> 16) & 1u)) >> 16);
}
__device__ __forceinline__ f4 cvt4(u16x4 u) {
    return (f4){bf2f(u.x), bf2f(u.y), bf2f(u.z), bf2f(u.w)};
}

// ---- K0: starts[] + bondKb = bf16(bond @ Ktop) (R13-proven fused prep) ----
__global__ __launch_bounds__(256)
void prep(const int* __restrict__ edges, int* __restrict__ starts,
          const float* __restrict__ bond, const float* __restrict__ Kmat,
          unsigned short* __restrict__ bondKb) {
    __shared__ float ldsK[64 * 64];
    const int tid = threadIdx.x;

    if (blockIdx.x < STARTS_BLOCKS) {
        const int e = blockIdx.x * 256 + tid;
        if (e >= N_EDGES) return;
        const int2* edges2 = (const int2*)edges;
        const int s  = edges2[e].x;
        const int sp = (e == 0) ? -1 : edges2[e - 1].x;
        for (int b = sp + 1; b <= s; ++b) starts[b] = e;
        if (e == N_EDGES - 1)
            for (int b = s + 1; b <= N_BONDS; ++b) starts[b] = N_EDGES;
        return;
    }

    const int bid  = blockIdx.x - STARTS_BLOCKS;
    const int lane = tid & 63;
    const int wid  = tid >> 6;
    {
        const f4* K4 = (const f4*)Kmat;            // Ktop = first 1024 f4
        f4* L4 = (f4*)ldsK;
        #pragma unroll
        for (int i = 0; i < 4; ++i) L4[tid + i * 256] = K4[tid + i * 256];
    }
    __syncthreads();
    const int row0 = bid * 32 + wid * 8;
    if (row0 >= N_BONDS) return;

    float rowv[8], acc[8];
    #pragma unroll
    for (int r = 0; r < 8; ++r) {
        int ri = row0 + r; if (ri >= N_BONDS) ri = N_BONDS - 1;
        rowv[r] = bond[ri * 64 + lane];
        acc[r]  = 0.f;
    }
    #pragma unroll 4
    for (int d = 0; d < 64; ++d) {
        const float k = ldsK[d * 64 + lane];       // lane = output unit
        #pragma unroll
        for (int r = 0; r < 8; ++r)
            acc[r] = fmaf(bcastf(rowv[r], d), k, acc[r]);
    }
    #pragma unroll
    for (int r = 0; r < 8; ++r)
        if (row0 + r < N_BONDS)
            bondKb[(row0 + r) * 64 + lane] = f2bf(acc[r]);
}

// ---- K1: wave-segregated segsum ----
// even blocks: GATHER (bondKb -> outG);  odd blocks: STREAM (sph -> Sbuf).
// Each wave's vmem queue holds ONE latency class only.
__global__ __launch_bounds__(THREADS, 8)   // no LDS, VGPR<=64
void split_segsum(const unsigned short* __restrict__ bondKb, // [N_BONDS][64] bf16
                  const float* __restrict__ sph,             // [N_EDGES][64]
                  const int*   __restrict__ edges,           // [N_EDGES][2]
                  const int*   __restrict__ starts,          // [N_BONDS+1]
                  float* __restrict__ outG,                  // = d_out
                  float* __restrict__ Sbuf)
{
    const int tid  = threadIdx.x;
    const int lane = tid & 63;
    const int wid  = tid >> 6;
    const int fl   = lane & 15;
    const int sg   = lane >> 4;
    const bool isStream = (blockIdx.x & 1);

    const int b0 = (blockIdx.x >> 1) * BONDS_PER_BLOCK + wid * R_BONDS;
    if (b0 >= N_BONDS) return;

    int st[R_BONDS + 1];                               // SGPR, static-indexed only
    #pragma unroll
    for (int r = 0; r <= R_BONDS; ++r)
        st[r] = __builtin_amdgcn_readfirstlane(starts[b0 + r]);

    const int eb    = st[0];
    const int total = st[R_BONDS] - eb;

    float slot[R_BONDS];                               // static-indexed only
    f4 aX = f4zero();
    int r = 0, cs = 0, bnd = st[1] - eb;

    // f4 layout -> scalar layout (lane d = feature d), summed over 4 subgroups
    auto txr = [&](f4 v) -> float {
        v.x += __shfl_xor(v.x, 16); v.y += __shfl_xor(v.y, 16);
        v.z += __shfl_xor(v.z, 16); v.w += __shfl_xor(v.w, 16);
        v.x += __shfl_xor(v.x, 32); v.y += __shfl_xor(v.y, 32);
        v.z += __shfl_xor(v.z, 32); v.w += __shfl_xor(v.w, 32);
        const int src = lane >> 2;
        const float s0 = __shfl(v.x, src), s1 = __shfl(v.y, src);
        const float s2 = __shfl(v.z, src), s3 = __shfl(v.w, src);
        const float r01 = (lane & 1) ? s1 : s0;
        const float r23 = (lane & 1) ? s3 : s2;
        return (lane & 2) ? r23 : r01;
    };

    // boundary path: masked add, close bonds that end inside this quad
    auto slowpath = [&](int q, f4 XV) {
        const int qe = q + sg;
        while (true) {
            const float m = (qe >= cs && qe < bnd) ? 1.f : 0.f;
            fma4(aX, m, XV);
            if (bnd > q + 4) break;
            const float tX = txr(aX);                  // close bond r
            #pragma unroll
            for (int rr = 0; rr < R_BONDS; ++rr)
                if (rr == r) slot[rr] = tX;
            aX = f4zero();
            cs = bnd;
            ++r;
            if (r >= R_BONDS) { bnd = 0x7fffffff; break; }
            #pragma unroll
            for (int rr = 2; rr <= R_BONDS; ++rr)
                if (r + 1 == rr) bnd = st[rr] - eb;
        }
    };
    auto accq = [&](int q_, f4 XV) {
        if (q_ + 4 <= bnd) aX += XV;
        else slowpath(q_, XV);
    };

    if (!isStream) {
        // ---------- GATHER side: only bondKb gathers in the queue ----------
        const u16x4* bk4    = (const u16x4*)bondKb;
        const int2*  edges2 = (const int2*)edges;
        int w0 = 0;
        while (w0 < total) {
            int wlen = total - w0; if (wlen > 64) wlen = 64;
            int2 p = make_int2(0, 0);
            if (lane < wlen) p = edges2[eb + w0 + lane];
            const int ng = (wlen + 3) >> 2;
            u16x4 uA, uB, uC, uD;

#define ISSG(QQ, UV) do { \
            if ((QQ) < ng) { \
                const int nbr_ = __shfl(p.y, (QQ) * 4 + sg); \
                UV = bk4[nbr_ * 16 + fl]; \
            } else UV = (u16x4){0,0,0,0}; } while (0)
#define ACCG(QQ, UV) accq(w0 + (QQ) * 4, cvt4(UV))

            ISSG(0, uA); ISSG(1, uB); ISSG(2, uC); ISSG(3, uD);
            int q = 0;
            for (; q + 4 <= ng; q += 4) {
                ACCG(q + 0, uA); ISSG(q + 4, uA);
                ACCG(q + 1, uB); ISSG(q + 5, uB);
                ACCG(q + 2, uC); ISSG(q + 6, uC);
                ACCG(q + 3, uD); ISSG(q + 7, uD);
            }
            if (q + 0 < ng) ACCG(q + 0, uA);
            if (q + 1 < ng) ACCG(q + 1, uB);
            if (q + 2 < ng) ACCG(q + 2, uC);
#undef ISSG
#undef ACCG
            w0 += wlen;
        }
    } else {
        // ---------- STREAM side: only linear sph reads in the queue ----------
        const f4* s4 = (const f4*)sph;
        const int nq = (total + 3) >> 2;
        f4 vA, vB, vC, vD;

#define ISSS(QQ, SV) do { \
        if ((QQ) < nq) { \
            int qe_ = (QQ) * 4 + sg; if (qe_ >= total) qe_ = total - 1; \
            SV = s4[(eb + qe_) * 16 + fl]; \
        } else SV = f4zero(); } while (0)
#define ACCS(QQ, SV) accq((QQ) * 4, SV)

        ISSS(0, vA); ISSS(1, vB); ISSS(2, vC); ISSS(3, vD);
        int q = 0;
        for (; q + 4 <= nq; q += 4) {
            ACCS(q + 0, vA); ISSS(q + 4, vA);
            ACCS(q + 1, vB); ISSS(q + 5, vB);
            ACCS(q + 2, vC); ISSS(q + 6, vC);
            ACCS(q + 3, vD); ISSS(q + 7, vD);
        }
        if (q + 0 < nq) ACCS(q + 0, vA);
        if (q + 1 < nq) ACCS(q + 1, vB);
        if (q + 2 < nq) ACCS(q + 2, vC);
#undef ISSS
#undef ACCS
    }

    {   // close remaining open/empty bonds
        const float tX = txr(aX);
        #pragma unroll
        for (int rr = 0; rr < R_BONDS; ++rr) {
            if (rr == r)     slot[rr] = tX;
            else if (rr > r) slot[rr] = 0.f;
        }
    }

    float* dst = isStream ? Sbuf : outG;
    #pragma unroll
    for (int rr = 0; rr < R_BONDS; ++rr)
        if (b0 + rr < N_BONDS)
            __builtin_nontemporal_store(slot[rr], &dst[(b0 + rr) * 64 + lane]);
}

// ---- K2: out = out(gather part) + Sbuf @ Kbot + bias (R11-proven) ----
__global__ __launch_bounds__(256, 4)
void finish_mm(const float* __restrict__ Sbuf, const float* __restrict__ Kmat,
               const float* __restrict__ bias, float* __restrict__ out) {
    __shared__ float ldsK[64 * 64];
    const int tid = threadIdx.x, lane = tid & 63, wid = tid >> 6;
    {
        const f4* K4 = (const f4*)Kmat;            // Kbot = f4 index 1024..2047
        f4* L4 = (f4*)ldsK;
        #pragma unroll
        for (int i = 0; i < 4; ++i) L4[tid + i * 256] = K4[1024 + tid + i * 256];
    }
    __syncthreads();
    const int row0 = blockIdx.x * 32 + wid * 8;
    if (row0 >= N_BONDS) return;

    const float bl = bias[lane];
    float rowv[8], acc[8];
    #pragma unroll
    for (int r = 0; r < 8; ++r) {
        int ri = row0 + r; if (ri >= N_BONDS) ri = N_BONDS - 1;
        rowv[r] = Sbuf[ri * 64 + lane];
        acc[r]  = out[ri * 64 + lane] + bl;
    }
    #pragma unroll 4
    for (int d = 0; d < 64; ++d) {
        const float k = ldsK[d * 64 + lane];
        #pragma unroll
        for (int r = 0; r < 8; ++r)
            acc[r] = fmaf(bcastf(rowv[r], d), k, acc[r]);
    }
    #pragma unroll
    for (int r = 0; r < 8; ++r)
        if (row0 + r < N_BONDS)
            __builtin_nontemporal_store(acc[r], &out[(row0 + r) * 64 + lane]);
}

extern "C" void kernel_launch(void* const* d_in, const int* in_sizes, int n_in,
                              void* d_out, int out_size, void* d_ws, size_t ws_size,
                              hipStream_t stream) {
    const float* bond  = (const float*)d_in[0];
    const float* sph   = (const float*)d_in[1];
    const int*   edges = (const int*)d_in[2];
    const float* Kmat  = (const float*)d_in[3];
    const float* bias  = (const float*)d_in[4];
    float* out = (float*)d_out;

    const size_t rowBytes = (size_t)N_BONDS * 64 * sizeof(float);   // 12.8 MB
    int*            starts = (int*)d_ws;                            // 200 KB
    float*          Sbuf   = (float*)((char*)d_ws + 262144);
    unsigned short* bondKb = (unsigned short*)((char*)d_ws + 262144 + rowBytes);

    prep<<<STARTS_BLOCKS + PREMUL_BLOCKS, 256, 0, stream>>>(edges, starts,
                                                            bond, Kmat, bondKb);

    split_segsum<<<2 * MAIN_BBLKS, THREADS, 0, stream>>>(bondKb, sph, edges,
                                                         starts, out, Sbuf);

    finish_mm<<<PREMUL_BLOCKS, 256, 0, stream>>>(Sbuf, Kmat, bias, out);
}

// Round 18
// 82.495 us; speedup vs baseline: 2.1077x; 1.0780x over previous
//
#include <hip/hip_runtime.h>

#define N_BONDS 50000
#define N_EDGES 600000
#define R_BONDS 4
#define THREADS 512
#define BONDS_PER_BLOCK 32   // 8 waves * 4 bonds

typedef float f4 __attribute__((ext_vector_type(4)));

__device__ __forceinline__ float bcastf(float v, int l) {
    return __builtin_bit_cast(float, __builtin_amdgcn_readlane(__builtin_bit_cast(int, v), l));
}
__device__ __forceinline__ f4 f4zero() { return (f4){0.f, 0.f, 0.f, 0.f}; }
__device__ __forceinline__ void fma4(f4& a, float s, const f4& b) {
    a.x = fmaf(s, b.x, a.x); a.y = fmaf(s, b.y, a.y);
    a.z = fmaf(s, b.z, a.z); a.w = fmaf(s, b.w, a.w);
}

// ---- kernel 1: starts[b] = lower_bound(seg, b), b in [0, N_BONDS] ----
__global__ __launch_bounds__(256)
void fill_starts(const int* __restrict__ edges, int* __restrict__ starts) {
    const int e = blockIdx.x * blockDim.x + threadIdx.x;
    if (e >= N_EDGES) return;
    const int2* edges2 = (const int2*)edges;
    const int s  = edges2[e].x;
    const int sp = (e == 0) ? -1 : edges2[e - 1].x;
    for (int b = sp + 1; b <= s; ++b) starts[b] = e;
    if (e == N_EDGES - 1)
        for (int b = s + 1; b <= N_BONDS; ++b) starts[b] = N_EDGES;
}

// ---- kernel 2: fused, queue-segregated: [idx][sph x8][gather x8] per block ----
__global__ __launch_bounds__(THREADS, 4)   // VGPR cap 128
void fused_gather_segsum_mm(const float* __restrict__ bond,   // [N_BONDS][64]
                            const float* __restrict__ sph,    // [N_EDGES][64]
                            const int*   __restrict__ edges,  // [N_EDGES][2]
                            const float* __restrict__ Kmat,   // [128][64]
                            const float* __restrict__ bias,   // [64]
                            const int*   __restrict__ starts, // [N_BONDS+1]
                            float* __restrict__ out)          // [N_BONDS][64]
{
    __shared__ float ldsK[128 * 64];   // 32 KB shared by 8 waves
    const int tid  = threadIdx.x;
    const int lane = tid & 63;
    const int wid  = tid >> 6;
    const int fl   = lane & 15;   // f4-column within a 64-float row
    const int sg   = lane >> 4;   // subgroup = edge-within-quad

    {   // stage K, coalesced 16B
        const f4* K4 = (const f4*)Kmat;
        f4*       L4 = (f4*)ldsK;
        #pragma unroll
        for (int i = 0; i < 4; ++i) L4[tid + i * THREADS] = K4[tid + i * THREADS];
    }
    __syncthreads();                                   // only barrier

    const int b0 = blockIdx.x * BONDS_PER_BLOCK + wid * R_BONDS;
    if (b0 >= N_BONDS) return;

    int st[R_BONDS + 1];                               // SGPR, static-indexed only
    #pragma unroll
    for (int r = 0; r <= R_BONDS; ++r)
        st[r] = __builtin_amdgcn_readfirstlane(starts[b0 + r]);

    const int eb    = st[0];
    const int total = st[R_BONDS] - eb;
    const int nq    = (total + 3) >> 2;                // quads

    const f4* bond4 = (const f4*)bond;
    const f4* sph4  = (const f4*)sph;

    // ---- two independent segment-walk state machines (S = sph, G = gather) ----
    float slotG[R_BONDS], slotS[R_BONDS];              // static-indexed only
    f4 aG = f4zero(), aS = f4zero();
    int rS = 0, csS = 0, bndS = st[1] - eb;
    int rG = 0, csG = 0, bndG = st[1] - eb;

    // cross-subgroup reduce + transpose f4 layout -> scalar layout (lane d = feat d)
    auto txr = [&](f4 v) -> float {
        v.x += __shfl_xor(v.x, 16); v.y += __shfl_xor(v.y, 16);
        v.z += __shfl_xor(v.z, 16); v.w += __shfl_xor(v.w, 16);
        v.x += __shfl_xor(v.x, 32); v.y += __shfl_xor(v.y, 32);
        v.z += __shfl_xor(v.z, 32); v.w += __shfl_xor(v.w, 32);
        const int src = lane >> 2;
        const float s0 = __shfl(v.x, src), s1 = __shfl(v.y, src);
        const float s2 = __shfl(v.z, src), s3 = __shfl(v.w, src);
        const float r01 = (lane & 1) ? s1 : s0;
        const float r23 = (lane & 1) ? s3 : s2;
        return (lane & 2) ? r23 : r01;
    };

    auto slowS = [&](int q, f4 XV) {
        const int qe = q + sg;
        while (true) {
            const float m = (qe >= csS && qe < bndS) ? 1.f : 0.f;
            fma4(aS, m, XV);
            if (bndS > q + 4) break;
            const float tX = txr(aS);
            #pragma unroll
            for (int rr = 0; rr < R_BONDS; ++rr) if (rr == rS) slotS[rr] = tX;
            aS = f4zero();
            csS = bndS;
            ++rS;
            if (rS >= R_BONDS) { bndS = 0x7fffffff; break; }
            #pragma unroll
            for (int rr = 2; rr <= R_BONDS; ++rr) if (rS + 1 == rr) bndS = st[rr] - eb;
        }
    };
    auto accS = [&](int Q, f4 XV) {
        const int q_ = Q * 4;
        if (q_ + 4 <= bndS) aS += XV; else slowS(q_, XV);
    };
    auto slowG = [&](int q, f4 XV) {
        const int qe = q + sg;
        while (true) {
            const float m = (qe >= csG && qe < bndG) ? 1.f : 0.f;
            fma4(aG, m, XV);
            if (bndG > q + 4) break;
            const float tX = txr(aG);
            #pragma unroll
            for (int rr = 0; rr < R_BONDS; ++rr) if (rr == rG) slotG[rr] = tX;
            aG = f4zero();
            csG = bndG;
            ++rG;
            if (rG >= R_BONDS) { bndG = 0x7fffffff; break; }
            #pragma unroll
            for (int rr = 2; rr <= R_BONDS; ++rr) if (rG + 1 == rr) bndG = st[rr] - eb;
        }
    };
    auto accG = [&](int Q, f4 XV) {
        const int q_ = Q * 4;
        if (q_ + 4 <= bndG) aG += XV; else slowG(q_, XV);
    };

    // subgroup-uniform index load (prefetched 1 block ahead; off the addr chain)
    auto loadIdx = [&](int Q) -> int {
        if (Q >= nq) return 0;                         // uniform guard: no load
        int e = 4 * Q + sg;
        e = (e < total) ? e : total - 1;
        return edges[2 * (eb + e) + 1];
    };
    auto loadSph = [&](int Q) -> f4 {
        int e = 4 * Q + sg;
        e = (e < total) ? e : total - 1;
        return sph4[(eb + e) * 16 + fl];
    };

    f4 v0, v1, v2, v3, v4, v5, v6, v7;                 // sph block (8 quads)
    f4 g0, g1, g2, g3, g4, g5, g6, g7;                 // gather block
    int ia0, ia1, ia2, ia3, ia4, ia5, ia6, ia7;
    int ib0, ib1, ib2, ib3, ib4, ib5, ib6, ib7;

    if (nq > 0) {
        ia0 = loadIdx(0); ia1 = loadIdx(1); ia2 = loadIdx(2); ia3 = loadIdx(3);
        ia4 = loadIdx(4); ia5 = loadIdx(5); ia6 = loadIdx(6); ia7 = loadIdx(7);

        for (int Q0 = 0; Q0 < nq; Q0 += 8) {
            // next block's indices (oldest in queue, consumed next iteration)
            ib0 = loadIdx(Q0 + 8);  ib1 = loadIdx(Q0 + 9);
            ib2 = loadIdx(Q0 + 10); ib3 = loadIdx(Q0 + 11);
            ib4 = loadIdx(Q0 + 12); ib5 = loadIdx(Q0 + 13);
            ib6 = loadIdx(Q0 + 14); ib7 = loadIdx(Q0 + 15);

            // ---- sph loads: FRONT of the queue (fast, linear) ----
            v0 = loadSph(Q0 + 0);
            v1 = (Q0 + 1 < nq) ? loadSph(Q0 + 1) : f4zero();
            v2 = (Q0 + 2 < nq) ? loadSph(Q0 + 2) : f4zero();
            v3 = (Q0 + 3 < nq) ? loadSph(Q0 + 3) : f4zero();
            v4 = (Q0 + 4 < nq) ? loadSph(Q0 + 4) : f4zero();
            v5 = (Q0 + 5 < nq) ? loadSph(Q0 + 5) : f4zero();
            v6 = (Q0 + 6 < nq) ? loadSph(Q0 + 6) : f4zero();
            v7 = (Q0 + 7 < nq) ? loadSph(Q0 + 7) : f4zero();
            __builtin_amdgcn_sched_barrier(0);         // sph strictly before gathers

            // ---- gathers: BACK of the queue (slow, random) ----
            g0 = bond4[ia0 * 16 + fl];
            g1 = (Q0 + 1 < nq) ? bond4[ia1 * 16 + fl] : f4zero();
            g2 = (Q0 + 2 < nq) ? bond4[ia2 * 16 + fl] : f4zero();
            g3 = (Q0 + 3 < nq) ? bond4[ia3 * 16 + fl] : f4zero();
            g4 = (Q0 + 4 < nq) ? bond4[ia4 * 16 + fl] : f4zero();
            g5 = (Q0 + 5 < nq) ? bond4[ia5 * 16 + fl] : f4zero();
            g6 = (Q0 + 6 < nq) ? bond4[ia6 * 16 + fl] : f4zero();
            g7 = (Q0 + 7 < nq) ? bond4[ia7 * 16 + fl] : f4zero();
            __builtin_amdgcn_sched_barrier(0);         // gathers before any acc

            // ---- accumulate sph half: waitcnt drains only idx+sph (older);
            //      the 8 gathers stay in flight under this VALU work ----
            accS(Q0 + 0, v0);
            if (Q0 + 1 < nq) accS(Q0 + 1, v1);
            if (Q0 + 2 < nq) accS(Q0 + 2, v2);
            if (Q0 + 3 < nq) accS(Q0 + 3, v3);
            if (Q0 + 4 < nq) accS(Q0 + 4, v4);
            if (Q0 + 5 < nq) accS(Q0 + 5, v5);
            if (Q0 + 6 < nq) accS(Q0 + 6, v6);
            if (Q0 + 7 < nq) accS(Q0 + 7, v7);

            // ---- accumulate gather half (completed under the shadow) ----
            accG(Q0 + 0, g0);
            if (Q0 + 1 < nq) accG(Q0 + 1, g1);
            if (Q0 + 2 < nq) accG(Q0 + 2, g2);
            if (Q0 + 3 < nq) accG(Q0 + 3, g3);
            if (Q0 + 4 < nq) accG(Q0 + 4, g4);
            if (Q0 + 5 < nq) accG(Q0 + 5, g5);
            if (Q0 + 6 < nq) accG(Q0 + 6, g6);
            if (Q0 + 7 < nq) accG(Q0 + 7, g7);

            ia0 = ib0; ia1 = ib1; ia2 = ib2; ia3 = ib3;
            ia4 = ib4; ia5 = ib5; ia6 = ib6; ia7 = ib7;
        }
    }

    {   // close remaining open/empty bonds, both walkers
        const float tS_ = txr(aS);
        #pragma unroll
        for (int rr = 0; rr < R_BONDS; ++rr) {
            if (rr == rS)     slotS[rr] = tS_;
            else if (rr > rS) slotS[rr] = 0.f;
        }
        const float tG_ = txr(aG);
        #pragma unroll
        for (int rr = 0; rr < R_BONDS; ++rr) {
            if (rr == rG)     slotG[rr] = tG_;
            else if (rr > rG) slotG[rr] = 0.f;
        }
    }

    // ---- deferred matvec: 4 bonds amortize each LDS K read ----
    float acc[R_BONDS];
    const float bl = bias[lane];
    #pragma unroll
    for (int rr = 0; rr < R_BONDS; ++rr) acc[rr] = bl;

    #pragma unroll 4
    for (int d = 0; d < 64; ++d) {
        const float kt = ldsK[d * 64 + lane];          // 2-way bank alias: free
        const float kb = ldsK[(64 + d) * 64 + lane];
        #pragma unroll
        for (int rr = 0; rr < R_BONDS; ++rr) {
            acc[rr] = fmaf(bcastf(slotG[rr], d), kt, acc[rr]);
            acc[rr] = fmaf(bcastf(slotS[rr], d), kb, acc[rr]);
        }
    }

    #pragma unroll
    for (int rr = 0; rr < R_BONDS; ++rr)
        if (b0 + rr < N_BONDS)
            __builtin_nontemporal_store(acc[rr], &out[(b0 + rr) * 64 + lane]);
}

extern "C" void kernel_launch(void* const* d_in, const int* in_sizes, int n_in,
                              void* d_out, int out_size, void* d_ws, size_t ws_size,
                              hipStream_t stream) {
    const float* bond  = (const float*)d_in[0];
    const float* sph   = (const float*)d_in[1];
    const int*   edges = (const int*)d_in[2];
    const float* Kmat  = (const float*)d_in[3];
    const float* bias  = (const float*)d_in[4];
    float* out  = (float*)d_out;
    int* starts = (int*)d_ws;                          // (N_BONDS+1)*4 = 200 KB

    fill_starts<<<(N_EDGES + 255) / 256, 256, 0, stream>>>(edges, starts);

    const int nblocks = (N_BONDS + BONDS_PER_BLOCK - 1) / BONDS_PER_BLOCK;
    fused_gather_segsum_mm<<<nblocks, THREADS, 0, stream>>>(bond, sph, edges, Kmat,
                                                            bias, starts, out);
}

// Round 19
// 81.816 us; speedup vs baseline: 2.1252x; 1.0083x over previous
//
#include <hip/hip_runtime.h>

#define N_BONDS 50000
#define N_EDGES 600000
#define THREADS 512
#define BONDS_PER_BLOCK 32
#define GB 8      // bonds per gather/stream wave (4 waves per class)

typedef float f4 __attribute__((ext_vector_type(4)));

__device__ __forceinline__ float bcastf(float v, int l) {
    return __builtin_bit_cast(float, __builtin_amdgcn_readlane(__builtin_bit_cast(int, v), l));
}
__device__ __forceinline__ f4 f4zero() { return (f4){0.f, 0.f, 0.f, 0.f}; }
__device__ __forceinline__ void fma4(f4& a, float s, const f4& b) {
    a.x = fmaf(s, b.x, a.x); a.y = fmaf(s, b.y, a.y);
    a.z = fmaf(s, b.z, a.z); a.w = fmaf(s, b.w, a.w);
}

// ---- kernel 1: starts[b] = lower_bound(seg, b), b in [0, N_BONDS] ----
__global__ __launch_bounds__(256)
void fill_starts(const int* __restrict__ edges, int* __restrict__ starts) {
    const int e = blockIdx.x * blockDim.x + threadIdx.x;
    if (e >= N_EDGES) return;
    const int2* edges2 = (const int2*)edges;
    const int s  = edges2[e].x;
    const int sp = (e == 0) ? -1 : edges2[e - 1].x;
    for (int b = sp + 1; b <= s; ++b) starts[b] = e;
    if (e == N_EDGES - 1)
        for (int b = s + 1; b <= N_BONDS; ++b) starts[b] = N_EDGES;
}

// ---- kernel 2: wave-split fused kernel ----
// waves 0-3: gather bond rows only.  waves 4-7: stream sph only (index-free).
// Each wave's vmem queue holds exactly ONE latency class.
__global__ __launch_bounds__(THREADS, 4)
void fused_wavesplit(const float* __restrict__ bond,   // [N_BONDS][64]
                     const float* __restrict__ sph,    // [N_EDGES][64]
                     const int*   __restrict__ edges,  // [N_EDGES][2]
                     const float* __restrict__ Kmat,   // [128][64]
                     const float* __restrict__ bias,   // [64]
                     const int*   __restrict__ starts, // [N_BONDS+1]
                     float* __restrict__ out)          // [N_BONDS][64]
{
    __shared__ float ldsK[128 * 64];              // 32 KB
    __shared__ float ldsG[BONDS_PER_BLOCK * 64];  // 8 KB  gather slots
    __shared__ float ldsS[BONDS_PER_BLOCK * 64];  // 8 KB  stream slots

    const int tid  = threadIdx.x;
    const int lane = tid & 63;
    const int wid  = tid >> 6;
    const int fl   = lane & 15;   // f4-column within a 64-float row
    const int sg   = lane >> 4;   // subgroup = edge-within-quad

    {   // stage K, coalesced 16B (2048 f4 / 512 threads)
        const f4* K4 = (const f4*)Kmat;
        f4*       L4 = (f4*)ldsK;
        #pragma unroll
        for (int i = 0; i < 4; ++i) L4[tid + i * THREADS] = K4[tid + i * THREADS];
    }

    const bool isStream = (wid >= 4);
    const int  grp = wid & 3;
    const int  b0  = blockIdx.x * BONDS_PER_BLOCK + grp * GB;

    int st[GB + 1];                               // SGPR, static-indexed only
    #pragma unroll
    for (int r = 0; r <= GB; ++r) {
        int ix = b0 + r; if (ix > N_BONDS) ix = N_BONDS;   // clamp (no early return!)
        st[r] = __builtin_amdgcn_readfirstlane(starts[ix]);
    }
    const int eb    = st[0];
    const int total = st[GB] - eb;
    const int nq    = (total + 3) >> 2;

    float slot[GB];                               // static-indexed only
    f4 aX = f4zero();
    int r = 0, cs = 0, bnd = st[1] - eb;

    // cross-subgroup reduce + transpose f4 layout -> scalar (lane d = feature d)
    auto txr = [&](f4 v) -> float {
        v.x += __shfl_xor(v.x, 16); v.y += __shfl_xor(v.y, 16);
        v.z += __shfl_xor(v.z, 16); v.w += __shfl_xor(v.w, 16);
        v.x += __shfl_xor(v.x, 32); v.y += __shfl_xor(v.y, 32);
        v.z += __shfl_xor(v.z, 32); v.w += __shfl_xor(v.w, 32);
        const int src = lane >> 2;
        const float s0 = __shfl(v.x, src), s1 = __shfl(v.y, src);
        const float s2 = __shfl(v.z, src), s3 = __shfl(v.w, src);
        const float r01 = (lane & 1) ? s1 : s0;
        const float r23 = (lane & 1) ? s3 : s2;
        return (lane & 2) ? r23 : r01;
    };

    // boundary path: masked add, close bonds ending inside this quad
    auto slowpath = [&](int q, f4 XV) {
        const int qe = q + sg;
        while (true) {
            const float m = (qe >= cs && qe < bnd) ? 1.f : 0.f;
            fma4(aX, m, XV);
            if (bnd > q + 4) break;
            const float tX = txr(aX);                  // close bond r
            #pragma unroll
            for (int rr = 0; rr < GB; ++rr)
                if (rr == r) slot[rr] = tX;
            aX = f4zero();
            cs = bnd;
            ++r;
            if (r >= GB) { bnd = 0x7fffffff; break; }
            #pragma unroll
            for (int rr = 2; rr <= GB; ++rr)
                if (r + 1 == rr) bnd = st[rr] - eb;
        }
    };
    auto accX = [&](int Q, f4 XV) {
        const int q_ = Q * 4;
        if (q_ + 4 <= bnd) aX += XV;
        else slowpath(q_, XV);
    };

    if (!isStream) {
        // ---------- GATHER wave: only bond-row gathers in the queue ----------
        const f4* bond4 = (const f4*)bond;
        auto loadIdx = [&](int Q) -> int {
            if (Q >= nq) return 0;                     // uniform guard: no load
            int e = 4 * Q + sg;
            e = (e < total) ? e : total - 1;
            return edges[2 * (eb + e) + 1];            // subgroup-uniform dword
        };
        if (nq > 0) {
            int ia0 = loadIdx(0), ia1 = loadIdx(1), ia2 = loadIdx(2), ia3 = loadIdx(3);
            int ib0 = loadIdx(4), ib1 = loadIdx(5), ib2 = loadIdx(6), ib3 = loadIdx(7);
            for (int Q = 0; Q < nq; Q += 4) {
                f4 x0 = bond4[ia0 * 16 + fl];
                f4 x1 = (Q + 1 < nq) ? bond4[ia1 * 16 + fl] : f4zero();
                f4 x2 = (Q + 2 < nq) ? bond4[ia2 * 16 + fl] : f4zero();
                f4 x3 = (Q + 3 < nq) ? bond4[ia3 * 16 + fl] : f4zero();
                ia0 = ib0; ia1 = ib1; ia2 = ib2; ia3 = ib3;
                ib0 = loadIdx(Q + 8);  ib1 = loadIdx(Q + 9);
                ib2 = loadIdx(Q + 10); ib3 = loadIdx(Q + 11);
                accX(Q + 0, x0);
                if (Q + 1 < nq) accX(Q + 1, x1);
                if (Q + 2 < nq) accX(Q + 2, x2);
                if (Q + 3 < nq) accX(Q + 3, x3);
            }
        }
    } else {
        // ---------- STREAM wave: only linear sph reads; no indices at all ----------
        const f4* sph4 = (const f4*)sph;
        for (int Q = 0; Q < nq; Q += 4) {
            int e0 = 4 * Q + sg;              e0 = (e0 < total) ? e0 : total - 1;
            int e1 = 4 * (Q + 1) + sg;        e1 = (e1 < total) ? e1 : total - 1;
            int e2 = 4 * (Q + 2) + sg;        e2 = (e2 < total) ? e2 : total - 1;
            int e3 = 4 * (Q + 3) + sg;        e3 = (e3 < total) ? e3 : total - 1;
            f4 x0 = sph4[(eb + e0) * 16 + fl];
            f4 x1 = (Q + 1 < nq) ? sph4[(eb + e1) * 16 + fl] : f4zero();
            f4 x2 = (Q + 2 < nq) ? sph4[(eb + e2) * 16 + fl] : f4zero();
            f4 x3 = (Q + 3 < nq) ? sph4[(eb + e3) * 16 + fl] : f4zero();
            accX(Q + 0, x0);
            if (Q + 1 < nq) accX(Q + 1, x1);
            if (Q + 2 < nq) accX(Q + 2, x2);
            if (Q + 3 < nq) accX(Q + 3, x3);
        }
    }

    {   // close remaining open/empty bonds
        const float tX = txr(aX);
        #pragma unroll
        for (int rr = 0; rr < GB; ++rr) {
            if (rr == r)     slot[rr] = tX;
            else if (rr > r) slot[rr] = 0.f;
        }
    }

    {   // publish slots (scalar layout: lane = feature; conflict-free)
        float* dstL = isStream ? ldsS : ldsG;
        #pragma unroll
        for (int rr = 0; rr < GB; ++rr)
            dstL[(grp * GB + rr) * 64 + lane] = slot[rr];
    }
    __syncthreads();                                   // only barrier

    // ---- deferred matvec: each wave handles 4 bonds from LDS slots ----
    const int mb = wid * 4;                            // bond offset within block
    float vg[4], vs[4], acc[4];
    const float bl = bias[lane];
    #pragma unroll
    for (int rr = 0; rr < 4; ++rr) {
        vg[rr] = ldsG[(mb + rr) * 64 + lane];
        vs[rr] = ldsS[(mb + rr) * 64 + lane];
        acc[rr] = bl;
    }

    #pragma unroll 4
    for (int d = 0; d < 64; ++d) {
        const float kt = ldsK[d * 64 + lane];          // 2-way bank alias: free
        const float kb = ldsK[(64 + d) * 64 + lane];
        #pragma unroll
        for (int rr = 0; rr < 4; ++rr) {
            acc[rr] = fmaf(bcastf(vg[rr], d), kt, acc[rr]);
            acc[rr] = fmaf(bcastf(vs[rr], d), kb, acc[rr]);
        }
    }

    const int ob = blockIdx.x * BONDS_PER_BLOCK + mb;
    #pragma unroll
    for (int rr = 0; rr < 4; ++rr)
        if (ob + rr < N_BONDS)
            __builtin_nontemporal_store(acc[rr], &out[(ob + rr) * 64 + lane]);
}

extern "C" void kernel_launch(void* const* d_in, const int* in_sizes, int n_in,
                              void* d_out, int out_size, void* d_ws, size_t ws_size,
                              hipStream_t stream) {
    const float* bond  = (const float*)d_in[0];
    const float* sph   = (const float*)d_in[1];
    const int*   edges = (const int*)d_in[2];
    const float* Kmat  = (const float*)d_in[3];
    const float* bias  = (const float*)d_in[4];
    float* out  = (float*)d_out;
    int* starts = (int*)d_ws;                          // (N_BONDS+1)*4 = 200 KB

    fill_starts<<<(N_EDGES + 255) / 256, 256, 0, stream>>>(edges, starts);

    const int nblocks = (N_BONDS + BONDS_PER_BLOCK - 1) / BONDS_PER_BLOCK;
    fused_wavesplit<<<nblocks, THREADS, 0, stream>>>(bond, sph, edges, Kmat,
                                                     bias, starts, out);
}